// Round 10
// baseline (5323.086 us; speedup 1.0000x reference)
//
#include <hip/hip_runtime.h>

// ---------------------------------------------------------------------------
// SimpleLSTM: 2-layer LSTM (B=32,T=512,D=512,H=1024) + output proj (O=512).
//   conv kernels : fp32 -> f16, weights rearranged into MFMA B-frag order
//   zx0_gemm     : Zx0[t][wg][m][c] = x@Wx0 + b0  (parallel over all T)
//   lstm_persist : SPLIT-ROLE persistent kernel (R17)
//   wd_gemm      : Y = H1 @ Wd + bd
// R4-R16 history: tree barrier 22.7->14.5; uncached h stores 8.3; merged
//   phase 7.6; t-indexed h (no fences) 6.6->5.8; batched loads 4.8 persist;
//   reader-detector+zx0-shadow 4.66ms. Barrier micro-structure variants
//   (flat R9, split R12, prefetch R13, all-poll R14, parallel-release R15)
//   all neutral-to-worse: the 256-WG sync DOMAIN itself is the floor.
// R17: SHRINK THE CRITICAL SYNC DOMAIN 256 -> 64 WGs.
//   A-group (WGs 0..63): layer-0 recurrence only. 64 gate-cols each,
//     Wh0 slice (128 KiB) in LDS. Loop: wait goA -> load h0(k) -> 256
//     MFMAs -> store h0(k+1) uncached -> drain -> plain-store private
//     slotA (zero RMW). A-WG0 wave0 = reader-detector (64 slots, 1/lane),
//     broadcasts 192 private go lines (3 stores/lane).
//   B-group (WGs 64..191): layer 1. 32 gate-cols each, Wx1+Wh1 (128 KiB)
//     in LDS. Waits goA(k) [h0(k)] and goB(k) [h1(k-1)]; goB published a
//     full period earlier by B-WG0's detector during ITS goA wait -> B's
//     barrier is fully hidden behind A's period. h1(k) has a step of
//     slack before its only consumers (B itself, wd_gemm after).
//   Critical path = A's 64-WG loop: 4x less arrival skew, shorter detect
//   round, 2.7x fewer MFMAs on the serial chain than the old merged step.
// ---------------------------------------------------------------------------

typedef _Float16 half8  __attribute__((ext_vector_type(8)));
typedef float    floatx4 __attribute__((ext_vector_type(4)));

// ws layout (bytes)
#define WREC_OFF   0UL            // [256 wg][3 mat][128 kc][16 c][8] f16 = 24 MiB
#define WX0_OFF    25165824UL     // [256 wg][64 kc][16 c][8] f16        = 4 MiB
#define WD_OFF     29360128UL     // [32 nt][128 kc][16 c][8] f16        = 1 MiB
#define XH_OFF     30408704UL     // [512 t][32 b][512 d] f16            = 16 MiB
#define ZX0_OFF    47185920UL     // [512 t][256 wg][32 m][16 c] f16     = 128 MiB
#define H1_OFF     181403648UL    // [512 t][32 m][1024 k] f16           = 32 MiB
#define H0_OFF     214958080UL    // [512 t][32 m][1024 k] f16           = 32 MiB
#define FLAGS_OFF  248512512UL    // 128 KiB: slotA[64] goA[192] slotB[128] goB[128], 256B stride

__device__ __forceinline__ float fsig(float x){ return 1.0f/(1.0f + __expf(-x)); }
__device__ __forceinline__ float ftanhf(float x){
  float e = __expf(2.0f*fabsf(x));
  float r = 1.0f - 2.0f/(e + 1.0f);
  return copysignf(r, x);
}

// ---------------- weight conversion ----------------------------------------
__global__ void conv_wrec(const float* __restrict__ Wh0,
                          const float* __restrict__ Wx1,
                          const float* __restrict__ Wh1,
                          _Float16* __restrict__ out){
  int idx = blockIdx.x*256 + threadIdx.x;          // ((wg*3+mat)*128+kc)*16+c
  if (idx >= 256*3*128*16) return;
  int c  = idx & 15;
  int t1 = idx >> 4;
  int kc = t1 & 127;
  int t2 = t1 >> 7;
  int mat = t2 % 3;
  int wg  = t2 / 3;
  const float* W = (mat==0) ? Wh0 : (mat==1) ? Wx1 : Wh1;
  int col = (c>>2)*1024 + wg*4 + (c&3);
  _Float16* o = out + (size_t)idx*8;
  #pragma unroll
  for (int j=0;j<8;++j) o[j] = (_Float16)W[(kc*8+j)*4096 + col];
}

__global__ void conv_wx0(const float* __restrict__ W, _Float16* __restrict__ out){
  int idx = blockIdx.x*256 + threadIdx.x;          // ((wg*64+kc)*16+c)
  if (idx >= 256*64*16) return;
  int c  = idx & 15;
  int kc = (idx >> 4) & 63;
  int wg = idx >> 10;
  int col = (c>>2)*1024 + wg*4 + (c&3);
  _Float16* o = out + (size_t)idx*8;
  #pragma unroll
  for (int j=0;j<8;++j) o[j] = (_Float16)W[(kc*8+j)*4096 + col];
}

__global__ void conv_wd(const float* __restrict__ W, _Float16* __restrict__ out){
  int idx = blockIdx.x*256 + threadIdx.x;          // ((nt*128+kc)*16+c)
  if (idx >= 32*128*16) return;
  int c  = idx & 15;
  int kc = (idx >> 4) & 127;
  int nt = idx >> 11;
  int col = nt*16 + c;
  _Float16* o = out + (size_t)idx*8;
  #pragma unroll
  for (int j=0;j<8;++j) o[j] = (_Float16)W[(kc*8+j)*512 + col];
}

// x[b][t][d] fp32 -> xh[t*32+b][d] f16  (time-major rows for zx0_gemm)
__global__ void conv_x(const float* __restrict__ x, _Float16* __restrict__ xh){
  int idx = blockIdx.x*256 + threadIdx.x;          // [bt][dq], dq = d/4
  if (idx >= 2097152) return;
  int dq = idx & 127;
  int bt = idx >> 7;          // t*32 + b
  int b  = bt & 31;
  int t  = bt >> 5;
  float4 v = ((const float4*)x)[(size_t)(b*512 + t)*128 + dq];
  _Float16* o = xh + (size_t)idx*4;
  o[0]=(_Float16)v.x; o[1]=(_Float16)v.y; o[2]=(_Float16)v.z; o[3]=(_Float16)v.w;
}

// ---------------- Zx0 = x @ Wx0 + b0 ---------------------------------------
__global__ __launch_bounds__(64) void zx0_gemm(const _Float16* __restrict__ xh,
                                               const _Float16* __restrict__ wx0a,
                                               const float* __restrict__ b0,
                                               _Float16* __restrict__ zx0){
  int t   = blockIdx.x;        // 512
  int wgg = blockIdx.y;        // 64 (covers 4 wg slices)
  int l = threadIdx.x, q = l>>4, c = l&15;
  floatx4 acc[2][4];
  #pragma unroll
  for (int g=0; g<4; ++g){
    int wg = wgg*4+g;
    float bv = b0[(c>>2)*1024 + wg*4 + (c&3)];
    acc[0][g] = (floatx4){bv,bv,bv,bv};
    acc[1][g] = (floatx4){bv,bv,bv,bv};
  }
  #pragma unroll 4
  for (int ks=0; ks<16; ++ks){
    int kc = ks*4 + q;
    half8 a0 = *(const half8*)(xh + (t*32      + c)*512 + kc*8);
    half8 a1 = *(const half8*)(xh + (t*32 + 16 + c)*512 + kc*8);
    #pragma unroll
    for (int g=0; g<4; ++g){
      int wg = wgg*4+g;
      half8 b = *(const half8*)(wx0a + ((size_t)(wg*64 + kc)*16 + c)*8);
      acc[0][g] = __builtin_amdgcn_mfma_f32_16x16x32_f16(a0,b,acc[0][g],0,0,0);
      acc[1][g] = __builtin_amdgcn_mfma_f32_16x16x32_f16(a1,b,acc[1][g],0,0,0);
    }
  }
  #pragma unroll
  for (int g=0; g<4; ++g){
    int wg = wgg*4+g;
    #pragma unroll
    for (int mt=0; mt<2; ++mt)
      #pragma unroll
      for (int r=0;r<4;++r){
        int m = mt*16 + q*4 + r;
        zx0[((size_t)(t*256 + wg)*32 + m)*16 + c] = (_Float16)acc[mt][g][r];
      }
  }
}

// ---------------- persistent recurrent kernel ------------------------------
#define AF(base, ks)  (*(const half8*)((base) + (ks)*32))
#define BF(w, ks)     (*(const half8*)((w) + (((ks)*4 + q)*16 + c)*8))

// gate exchange + cell update + packed agent-scope store of h (cols wgo*4..+3)
__device__ __forceinline__ void gates_store(floatx4 acc, float* cs,
    _Float16* dst, int g, int c, int mt, int q, int wgo){
  #pragma unroll
  for (int r=0;r<4;++r){
    float v0 = acc[r];
    float v1 = __shfl_xor(v0, 4, 64);
    float v2 = __shfl_xor(v0, 8, 64);
    float v3 = __shfl_xor(v1, 8, 64);
    float zi = (g==0)?v0:(g==1)?v1:(g==2)?v2:v3;
    float zf = (g==0)?v1:(g==1)?v0:(g==2)?v3:v2;
    float zg = (g==0)?v2:(g==1)?v3:(g==2)?v0:v1;
    float zo = (g==0)?v3:(g==1)?v2:(g==2)?v1:v0;
    float cn = fsig(zf)*cs[r] + fsig(zi)*ftanhf(zg);
    cs[r] = cn;
    float hv = fsig(zo)*ftanhf(cn);
    unsigned hb16 = (unsigned)__builtin_bit_cast(unsigned short, (_Float16)hv);
    unsigned up   = (unsigned)__shfl_xor((int)hb16, 1, 64);
    if (g==0 && (c&1)==0)
      __hip_atomic_store((unsigned*)(dst + (mt*16 + q*4 + r)*1024 + wgo*4 + c),
                         hb16 | (up<<16),
                         __ATOMIC_RELAXED, __HIP_MEMORY_SCOPE_AGENT);
  }
}

#define LDU(p) __hip_atomic_load((p), __ATOMIC_RELAXED, __HIP_MEMORY_SCOPE_AGENT)
#define STU(p,v) __hip_atomic_store((p), (v), __ATOMIC_RELAXED, __HIP_MEMORY_SCOPE_AGENT)

__global__ __launch_bounds__(128, 1) void lstm_persist(
    const _Float16* __restrict__ wrec, const _Float16* __restrict__ zx0,
    const float* __restrict__ b1g, _Float16* __restrict__ h0a,
    _Float16* __restrict__ h1a, unsigned int* __restrict__ flags)
{
  extern __shared__ _Float16 lds[];   // 131072 B: 4 x [128 kc][16 c][8] slices

  const int wg = blockIdx.x, tid = threadIdx.x;
  const int wv = tid>>6, l = tid&63, q = l>>4, c = l&15;
  const int g = (c>>2);
  const int mt = wv;                  // wave0 rows 0-15, wave1 rows 16-31
  const int row = mt*16 + c;

  unsigned int* slotA = flags;                 // [64]  @ a*64  (256B stride)
  unsigned int* goA   = flags + 4096;          // [192] @ w*64
  unsigned int* slotB = flags + 16384;         // [128] @ b*64
  unsigned int* goB   = flags + 24576;         // [128] @ b*64

  if (wg < 64){
    // ================= A-group: layer-0 recurrence =================
    const int a = wg;
    // stage Wh0 slices for old-wg 4a..4a+3 (mat 0): 4 x 32 KiB
    #pragma unroll
    for (int j=0;j<4;++j){
      const uint4* src = (const uint4*)(wrec + ((size_t)(4*a+j)*3 + 0)*16384);
      uint4* dst = (uint4*)(lds + j*16384);
      for (int i=tid;i<2048;i+=128) dst[i]=src[i];
    }
    float c0s[4][4] = {{0,0,0,0},{0,0,0,0},{0,0,0,0},{0,0,0,0}};

    // prologue: h0(0) = act(zx0[0])  (h0(-1)=0)
    #pragma unroll
    for (int j=0;j<4;++j){
      const _Float16* zsrc = zx0 + ((size_t)(4*a+j)*32 + mt*16 + q*4)*16 + c;
      floatx4 z;
      z[0]=(float)zsrc[0]; z[1]=(float)zsrc[16]; z[2]=(float)zsrc[32]; z[3]=(float)zsrc[48];
      gates_store(z, c0s[j], h0a, g, c, mt, q, 4*a+j);
    }
    __syncthreads();                           // drain h0(0) stores
    if (tid==0) STU(slotA + a*64, 1u);

    for (int k=0;k<511;++k){
      const unsigned tgt = (unsigned)(k+1);    // h0(k) readable at goA>=k+1
      // zx0 prefetch for h0(k+1): completes in the wait shadow
      float pz[4][4];
      #pragma unroll
      for (int j=0;j<4;++j){
        const _Float16* zsrc = zx0 + ((size_t)((k+1)*256 + 4*a+j)*32 + mt*16 + q*4)*16 + c;
        pz[j][0]=(float)zsrc[0]; pz[j][1]=(float)zsrc[16];
        pz[j][2]=(float)zsrc[32]; pz[j][3]=(float)zsrc[48];
      }
      if (a==0 && wv==0){
        // reader-detector: lane l polls slotA[l]; then 192-line go burst
        for(;;){
          unsigned v = LDU(slotA + l*64);
          if (__ballot(v >= tgt) == 0xffffffffffffffffULL) break;
        }
        #pragma unroll
        for (int m=0;m<3;++m) STU(goA + (size_t)(m*64+l)*64, tgt);
      } else if (a!=0 && tid==0){
        while (LDU(goA + (size_t)a*64) < tgt) ;
      }
      __syncthreads();
      // fresh-line invariant: h0a[k] never cached by any XCD before this read

      const _Float16* h0c = h0a + (size_t)k*32768 + row*1024 + q*8;
      half8 H0[32];
      #pragma unroll
      for (int s=0;s<32;++s) H0[s] = AF(h0c, s);

      floatx4 acc[4], acc2[4];
      #pragma unroll
      for (int j=0;j<4;++j){ acc[j]=(floatx4){0,0,0,0}; acc2[j]=(floatx4){0,0,0,0}; }
      #pragma unroll
      for (int s=0;s<16;++s){
        #pragma unroll
        for (int j=0;j<4;++j){
          acc[j]  = __builtin_amdgcn_mfma_f32_16x16x32_f16(H0[s],    BF(lds + j*16384, s),    acc[j], 0,0,0);
          acc2[j] = __builtin_amdgcn_mfma_f32_16x16x32_f16(H0[16+s], BF(lds + j*16384, 16+s), acc2[j],0,0,0);
        }
      }
      #pragma unroll
      for (int j=0;j<4;++j){
        floatx4 z = acc[j] + acc2[j];
        z[0]+=pz[j][0]; z[1]+=pz[j][1]; z[2]+=pz[j][2]; z[3]+=pz[j][3];
        gates_store(z, c0s[j], h0a + (size_t)(k+1)*32768, g, c, mt, q, 4*a+j);
      }
      __syncthreads();                         // drain h0(k+1) stores
      if (tid==0) STU(slotA + a*64, (unsigned)(k+2));
    }
    // final release so B-step 511 can read h0(511)
    if (a==0 && wv==0){
      for(;;){
        unsigned v = LDU(slotA + l*64);
        if (__ballot(v >= 512u) == 0xffffffffffffffffULL) break;
      }
      #pragma unroll
      for (int m=0;m<3;++m) STU(goA + (size_t)(m*64+l)*64, 512u);
    }
  } else {
    // ================= B-group: layer-1 =================
    const int b = wg - 64;                     // 0..127, owns old-wg 2b,2b+1
    #pragma unroll
    for (int j=0;j<2;++j){                     // Wx1 slices
      const uint4* src = (const uint4*)(wrec + ((size_t)(2*b+j)*3 + 1)*16384);
      uint4* dst = (uint4*)(lds + j*16384);
      for (int i=tid;i<2048;i+=128) dst[i]=src[i];
    }
    #pragma unroll
    for (int j=0;j<2;++j){                     // Wh1 slices
      const uint4* src = (const uint4*)(wrec + ((size_t)(2*b+j)*3 + 2)*16384);
      uint4* dst = (uint4*)(lds + (2+j)*16384);
      for (int i=tid;i<2048;i+=128) dst[i]=src[i];
    }
    float c1s[2][4] = {{0,0,0,0},{0,0,0,0}};
    float b1v[2];
    #pragma unroll
    for (int j=0;j<2;++j) b1v[j] = b1g[g*1024 + (2*b+j)*4 + (c&3)];

    for (int k=0;k<512;++k){
      const unsigned tgtA = (unsigned)(k+1);   // h0(k) readable
      if (b==0 && wv==0){
        if (k > 0){
          // detect B arrivals (value k = h1(k-1) stored) + 128-line burst
          for(;;){
            unsigned va = LDU(slotB + l*64);
            unsigned vb = LDU(slotB + (size_t)(64+l)*64);
            if (__ballot((va >= (unsigned)k) & (vb >= (unsigned)k)) ==
                0xffffffffffffffffULL) break;
          }
          #pragma unroll
          for (int m=0;m<2;++m) STU(goB + (size_t)(m*64+l)*64, (unsigned)k);
        }
        if (l==0){
          while (LDU(goA + (size_t)64*64) < tgtA) ;
        }
      } else if (b!=0 && tid==0){
        while (LDU(goA + (size_t)(64+b)*64) < tgtA) ;
        if (k > 0)
          while (LDU(goB + (size_t)b*64) < (unsigned)k) ;
      }
      __syncthreads();

      // loads: H0 first (consumed first), H1 overlaps
      const _Float16* h0c = h0a + (size_t)k*32768 + row*1024 + q*8;
      half8 H0[32];
      #pragma unroll
      for (int s=0;s<32;++s) H0[s] = AF(h0c, s);
      half8 H1[32];
      if (k > 0){
        const _Float16* h1p = h1a + (size_t)(k-1)*32768 + row*1024 + q*8;
        #pragma unroll
        for (int s=0;s<32;++s) H1[s] = AF(h1p, s);
      }

      floatx4 acc[2], acc2[2];
      #pragma unroll
      for (int j=0;j<2;++j){
        acc[j] = (floatx4){b1v[j],b1v[j],b1v[j],b1v[j]};
        acc2[j] = (floatx4){0,0,0,0};
      }
      #pragma unroll
      for (int s=0;s<16;++s){
        #pragma unroll
        for (int j=0;j<2;++j){
          acc[j]  = __builtin_amdgcn_mfma_f32_16x16x32_f16(H0[s],    BF(lds + j*16384, s),    acc[j], 0,0,0);
          acc2[j] = __builtin_amdgcn_mfma_f32_16x16x32_f16(H0[16+s], BF(lds + j*16384, 16+s), acc2[j],0,0,0);
        }
      }
      if (k > 0){
        #pragma unroll
        for (int s=0;s<16;++s){
          #pragma unroll
          for (int j=0;j<2;++j){
            acc[j]  = __builtin_amdgcn_mfma_f32_16x16x32_f16(H1[s],    BF(lds + (2+j)*16384, s),    acc[j], 0,0,0);
            acc2[j] = __builtin_amdgcn_mfma_f32_16x16x32_f16(H1[16+s], BF(lds + (2+j)*16384, 16+s), acc2[j],0,0,0);
          }
        }
      }
      #pragma unroll
      for (int j=0;j<2;++j){
        floatx4 z = acc[j] + acc2[j];
        gates_store(z, c1s[j], h1a + (size_t)k*32768, g, c, mt, q, 2*b+j);
      }
      __syncthreads();                         // drain h1(k) stores
      if (tid==0) STU(slotB + (size_t)b*64, (unsigned)(k+1));
    }
  }
}

// ---------------- Y = H1 @ Wd + bd -----------------------------------------
__global__ __launch_bounds__(256) void wd_gemm(const _Float16* __restrict__ h1a,
                                               const _Float16* __restrict__ wda,
                                               const float* __restrict__ bd,
                                               float* __restrict__ y){
  int mb = blockIdx.x;   // 512 blocks of 32 rows (rows = t*32+b)
  int nb = blockIdx.y;   // 4 blocks of 128 cols
  int tid = threadIdx.x, wv = tid>>6, l = tid&63, q = l>>4, c = l&15;
  int mt = wv & 1, nh = wv >> 1;
  floatx4 acc[4];
  #pragma unroll
  for (int gg=0; gg<4; ++gg) acc[gg] = (floatx4){0.f,0.f,0.f,0.f};
  const _Float16* arow = h1a + (size_t)(mb*32 + mt*16 + c)*1024;
  #pragma unroll 4
  for (int ks=0; ks<32; ++ks){
    int kc = ks*4 + q;
    half8 a = *(const half8*)(arow + kc*8);
    #pragma unroll
    for (int gg=0; gg<4; ++gg){
      int nt = nb*8 + nh*4 + gg;
      half8 b = *(const half8*)(wda + ((size_t)(nt*128 + kc)*16 + c)*8);
      acc[gg] = __builtin_amdgcn_mfma_f32_16x16x32_f16(a,b,acc[gg],0,0,0);
    }
  }
  #pragma unroll
  for (int gg=0; gg<4; ++gg){
    int o = nb*128 + nh*64 + gg*16 + c;
    float bdv = bd[o];
    #pragma unroll
    for (int r=0;r<4;++r){
      int row = mb*32 + mt*16 + q*4 + r;
      int tt = row >> 5, bb = row & 31;
      y[(size_t)bb*262144 + tt*512 + o] = acc[gg][r] + bdv;
    }
  }
}

// ---------------------------------------------------------------------------
extern "C" void kernel_launch(void* const* d_in, const int* in_sizes, int n_in,
                              void* d_out, int out_size, void* d_ws, size_t ws_size,
                              hipStream_t stream){
  const float* x   = (const float*)d_in[0];
  const float* Wx0 = (const float*)d_in[1];
  const float* Wh0 = (const float*)d_in[2];
  const float* b0  = (const float*)d_in[3];
  const float* Wx1 = (const float*)d_in[4];
  const float* Wh1 = (const float*)d_in[5];
  const float* b1  = (const float*)d_in[6];
  const float* Wd  = (const float*)d_in[7];
  const float* bd  = (const float*)d_in[8];
  float* y = (float*)d_out;
  char* ws = (char*)d_ws;

  _Float16* wrec = (_Float16*)(ws + WREC_OFF);
  _Float16* wx0a = (_Float16*)(ws + WX0_OFF);
  _Float16* wda  = (_Float16*)(ws + WD_OFF);
  _Float16* xh   = (_Float16*)(ws + XH_OFF);
  _Float16* zx0  = (_Float16*)(ws + ZX0_OFF);
  _Float16* h1a  = (_Float16*)(ws + H1_OFF);
  _Float16* h0a  = (_Float16*)(ws + H0_OFF);
  unsigned int* flags = (unsigned int*)(ws + FLAGS_OFF);

  hipMemsetAsync(flags, 0, 131072, stream);
  conv_wrec<<<dim3(6144), dim3(256), 0, stream>>>(Wh0, Wx1, Wh1, wrec);
  conv_wx0 <<<dim3(1024), dim3(256), 0, stream>>>(Wx0, wx0a);
  conv_wd  <<<dim3(256),  dim3(256), 0, stream>>>(Wd, wda);
  conv_x   <<<dim3(8192), dim3(256), 0, stream>>>(x, xh);
  zx0_gemm <<<dim3(512,64), dim3(64), 0, stream>>>(xh, wx0a, b0, zx0);
  hipFuncSetAttribute((const void*)lstm_persist,
                      hipFuncAttributeMaxDynamicSharedMemorySize, 131072);
  lstm_persist<<<dim3(192), dim3(128), 131072, stream>>>(wrec, zx0, b1, h0a, h1a, flags);
  wd_gemm  <<<dim3(512,4), dim3(256), 0, stream>>>(h1a, wda, bd, y);
}

// Round 11
// 5226.592 us; speedup vs baseline: 1.0185x; 1.0185x over previous
//
#include <hip/hip_runtime.h>

// ---------------------------------------------------------------------------
// SimpleLSTM: 2-layer LSTM (B=32,T=512,D=512,H=1024) + output proj (O=512).
//   conv kernels : fp32 -> f16, weights rearranged into MFMA B-frag order
//   zx0_gemm     : Zx0[t][wg][m][c] = x@Wx0 + b0  (parallel over all T)
//   lstm_persist : 256 persistent WGs (1/CU), recurrent weights in LDS
//   wd_gemm      : Y = H1 @ Wd + bd
// R4-R16: tree barrier 14.5; uncached h stores 8.3; merged phase 7.6;
//   t-indexed h / no fences 6.6->5.8; batched loads 4.8; reader-detector +
//   zx0-shadow 4.66ms persist (best). Structural variants all failed:
//   flat R9, fused R11, split R12, prefetch R13, all-poll R14, parallel
//   release R15 (neutral), role-split R17 (regressed, h0 fan-out doubled).
//   Lesson: the period is a chain of fabric latencies; only removing
//   elements from the chain wins.
// R18: WAVE-DECOUPLED SYNC, ZERO RMW, ZERO PER-STEP s_barrier.
//   The two waves of a WG are fully independent in compute (disjoint rows,
//   intra-wave gate shfl). So:
//   (a) producer: each wave drains ITS stores (s_waitcnt vmcnt(0)) and
//       plain-stores its own slot dword (2 dwords packed in 8B per WG
//       line; no fetch_add queueing, no producer __syncthreads).
//   (b) detector (WG0 wave0): scans 256 slot lines as b64 (4/lane, 1 RTT
//       per round), bursts 256 private go lines (4 stores/lane).
//   (c) consumer: each wave's lane0 polls the private go line itself;
//       divergence reconvergence orders the loads; compiler fence stops
//       hoisting. No consumer __syncthreads.
//   Deletes: 2 s_barrier/step, leaf-RMW serialization, wave-skew coupling.
// ---------------------------------------------------------------------------

typedef _Float16 half8  __attribute__((ext_vector_type(8)));
typedef float    floatx4 __attribute__((ext_vector_type(4)));

// ws layout (bytes)
#define WREC_OFF   0UL            // [256 wg][3 mat][128 kc][16 c][8] f16 = 24 MiB
#define WX0_OFF    25165824UL     // [256 wg][64 kc][16 c][8] f16        = 4 MiB
#define WD_OFF     29360128UL     // [32 nt][128 kc][16 c][8] f16        = 1 MiB
#define XH_OFF     30408704UL     // [512 t][32 b][512 d] f16            = 16 MiB
#define ZX0_OFF    47185920UL     // [512 t][256 wg][32 m][16 c] f16     = 128 MiB
#define H1_OFF     181403648UL    // [512 t][32 m][1024 k] f16           = 32 MiB
#define H0_OFF     214958080UL    // [512 t][32 m][1024 k] f16           = 32 MiB
#define FLAGS_OFF  248512512UL    // 128 KiB: slot[256]@256B (2 dw/line), go[256]@256B

__device__ __forceinline__ float fsig(float x){ return 1.0f/(1.0f + __expf(-x)); }
__device__ __forceinline__ float ftanhf(float x){
  float e = __expf(2.0f*fabsf(x));
  float r = 1.0f - 2.0f/(e + 1.0f);
  return copysignf(r, x);
}

// ---------------- weight conversion ----------------------------------------
__global__ void conv_wrec(const float* __restrict__ Wh0,
                          const float* __restrict__ Wx1,
                          const float* __restrict__ Wh1,
                          _Float16* __restrict__ out){
  int idx = blockIdx.x*256 + threadIdx.x;          // ((wg*3+mat)*128+kc)*16+c
  if (idx >= 256*3*128*16) return;
  int c  = idx & 15;
  int t1 = idx >> 4;
  int kc = t1 & 127;
  int t2 = t1 >> 7;
  int mat = t2 % 3;
  int wg  = t2 / 3;
  const float* W = (mat==0) ? Wh0 : (mat==1) ? Wx1 : Wh1;
  int col = (c>>2)*1024 + wg*4 + (c&3);
  _Float16* o = out + (size_t)idx*8;
  #pragma unroll
  for (int j=0;j<8;++j) o[j] = (_Float16)W[(kc*8+j)*4096 + col];
}

__global__ void conv_wx0(const float* __restrict__ W, _Float16* __restrict__ out){
  int idx = blockIdx.x*256 + threadIdx.x;          // ((wg*64+kc)*16+c)
  if (idx >= 256*64*16) return;
  int c  = idx & 15;
  int kc = (idx >> 4) & 63;
  int wg = idx >> 10;
  int col = (c>>2)*1024 + wg*4 + (c&3);
  _Float16* o = out + (size_t)idx*8;
  #pragma unroll
  for (int j=0;j<8;++j) o[j] = (_Float16)W[(kc*8+j)*4096 + col];
}

__global__ void conv_wd(const float* __restrict__ W, _Float16* __restrict__ out){
  int idx = blockIdx.x*256 + threadIdx.x;          // ((nt*128+kc)*16+c)
  if (idx >= 32*128*16) return;
  int c  = idx & 15;
  int kc = (idx >> 4) & 127;
  int nt = idx >> 11;
  int col = nt*16 + c;
  _Float16* o = out + (size_t)idx*8;
  #pragma unroll
  for (int j=0;j<8;++j) o[j] = (_Float16)W[(kc*8+j)*512 + col];
}

// x[b][t][d] fp32 -> xh[t*32+b][d] f16  (time-major rows for zx0_gemm)
__global__ void conv_x(const float* __restrict__ x, _Float16* __restrict__ xh){
  int idx = blockIdx.x*256 + threadIdx.x;          // [bt][dq], dq = d/4
  if (idx >= 2097152) return;
  int dq = idx & 127;
  int bt = idx >> 7;          // t*32 + b
  int b  = bt & 31;
  int t  = bt >> 5;
  float4 v = ((const float4*)x)[(size_t)(b*512 + t)*128 + dq];
  _Float16* o = xh + (size_t)idx*4;
  o[0]=(_Float16)v.x; o[1]=(_Float16)v.y; o[2]=(_Float16)v.z; o[3]=(_Float16)v.w;
}

// ---------------- Zx0 = x @ Wx0 + b0 ---------------------------------------
__global__ __launch_bounds__(64) void zx0_gemm(const _Float16* __restrict__ xh,
                                               const _Float16* __restrict__ wx0a,
                                               const float* __restrict__ b0,
                                               _Float16* __restrict__ zx0){
  int t   = blockIdx.x;        // 512
  int wgg = blockIdx.y;        // 64 (covers 4 wg slices)
  int l = threadIdx.x, q = l>>4, c = l&15;
  floatx4 acc[2][4];
  #pragma unroll
  for (int g=0; g<4; ++g){
    int wg = wgg*4+g;
    float bv = b0[(c>>2)*1024 + wg*4 + (c&3)];
    acc[0][g] = (floatx4){bv,bv,bv,bv};
    acc[1][g] = (floatx4){bv,bv,bv,bv};
  }
  #pragma unroll 4
  for (int ks=0; ks<16; ++ks){
    int kc = ks*4 + q;
    half8 a0 = *(const half8*)(xh + (t*32      + c)*512 + kc*8);
    half8 a1 = *(const half8*)(xh + (t*32 + 16 + c)*512 + kc*8);
    #pragma unroll
    for (int g=0; g<4; ++g){
      int wg = wgg*4+g;
      half8 b = *(const half8*)(wx0a + ((size_t)(wg*64 + kc)*16 + c)*8);
      acc[0][g] = __builtin_amdgcn_mfma_f32_16x16x32_f16(a0,b,acc[0][g],0,0,0);
      acc[1][g] = __builtin_amdgcn_mfma_f32_16x16x32_f16(a1,b,acc[1][g],0,0,0);
    }
  }
  #pragma unroll
  for (int g=0; g<4; ++g){
    int wg = wgg*4+g;
    #pragma unroll
    for (int mt=0; mt<2; ++mt)
      #pragma unroll
      for (int r=0;r<4;++r){
        int m = mt*16 + q*4 + r;
        zx0[((size_t)(t*256 + wg)*32 + m)*16 + c] = (_Float16)acc[mt][g][r];
      }
  }
}

// ---------------- persistent recurrent kernel ------------------------------
// LDS: w0 (Wh0), w1 (Wx1), w2 (Wh1): [128 kc][16 c][8] each = 96 KiB total
#define AF(base, ks)  (*(const half8*)((base) + (ks)*32))
#define BF(w, ks)     (*(const half8*)((w) + (((ks)*4 + q)*16 + c)*8))

#define LDU(p)  __hip_atomic_load((p),  __ATOMIC_RELAXED, __HIP_MEMORY_SCOPE_AGENT)
#define STU(p,v) __hip_atomic_store((p), (v), __ATOMIC_RELAXED, __HIP_MEMORY_SCOPE_AGENT)
#define LDU64(p) __hip_atomic_load((const unsigned long long*)(p), \
                                   __ATOMIC_RELAXED, __HIP_MEMORY_SCOPE_AGENT)

// gate exchange + cell update + packed agent-scope store of h (cols wg*4..+3)
__device__ __forceinline__ void gates_store(floatx4 acc, float* cs,
    _Float16* dst, int g, int c, int mt, int q, int wg){
  #pragma unroll
  for (int r=0;r<4;++r){
    float v0 = acc[r];
    float v1 = __shfl_xor(v0, 4, 64);
    float v2 = __shfl_xor(v0, 8, 64);
    float v3 = __shfl_xor(v1, 8, 64);
    float zi = (g==0)?v0:(g==1)?v1:(g==2)?v2:v3;
    float zf = (g==0)?v1:(g==1)?v0:(g==2)?v3:v2;
    float zg = (g==0)?v2:(g==1)?v3:(g==2)?v0:v1;
    float zo = (g==0)?v3:(g==1)?v2:(g==2)?v1:v0;
    float cn = fsig(zf)*cs[r] + fsig(zi)*ftanhf(zg);
    cs[r] = cn;
    float hv = fsig(zo)*ftanhf(cn);
    unsigned hb16 = (unsigned)__builtin_bit_cast(unsigned short, (_Float16)hv);
    unsigned up   = (unsigned)__shfl_xor((int)hb16, 1, 64);
    if (g==0 && (c&1)==0)
      __hip_atomic_store((unsigned*)(dst + (mt*16 + q*4 + r)*1024 + wg*4 + c),
                         hb16 | (up<<16),
                         __ATOMIC_RELAXED, __HIP_MEMORY_SCOPE_AGENT);
  }
}

__global__ __launch_bounds__(128, 1) void lstm_persist(
    const _Float16* __restrict__ wrec, const _Float16* __restrict__ zx0,
    const float* __restrict__ b1g, _Float16* __restrict__ h0a,
    _Float16* __restrict__ h1a, unsigned int* __restrict__ flags)
{
  extern __shared__ _Float16 lds[];
  _Float16* w0  = lds;            // 16384 halves
  _Float16* w1  = lds + 16384;
  _Float16* w2  = lds + 32768;

  const int wg = blockIdx.x, tid = threadIdx.x;
  const int wv = tid>>6, l = tid&63, q = l>>4, c = l&15;
  const int g = (c>>2);           // gate of own column
  const int mt = wv;              // wave0 rows 0-15, wave1 rows 16-31
  const int row = mt*16 + c;      // A-frag row this lane loads

  unsigned int* slot = flags + (size_t)wg*64;           // dword[wv] of own line
  unsigned int* go   = flags + 16384 + (size_t)wg*64;   // private go line

  { // stage this WG's weight slice: 98304 B = 6144 uint4
    const uint4* src = (const uint4*)(wrec + (size_t)wg*49152);
    uint4* dst = (uint4*)lds;
    for (int i=tid; i<6144; i+=128) dst[i] = src[i];
  }
  float c0[4] = {0,0,0,0}, c1[4] = {0,0,0,0};
  const float b1v = b1g[g*1024 + wg*4 + (c&3)];
  __syncthreads();   // weights staged (only barrier in the kernel)

  // ---------- prologue: A(0): h0(0) = act(Zx0[0]) (h0(-1)=0) ----------
  {
    const _Float16* zsrc = zx0 + ((size_t)wg*32 + mt*16 + q*4)*16 + c;
    floatx4 a;
    a[0]=(float)zsrc[0]; a[1]=(float)zsrc[16]; a[2]=(float)zsrc[32]; a[3]=(float)zsrc[48];
    gates_store(a, c0, h0a, g, c, mt, q, wg);   // t = 0
  }
  asm volatile("s_waitcnt vmcnt(0)" ::: "memory");   // this wave's h0(0) at LLC
  if (l == 0) STU(slot + wv, 1u);

  for (int t=0; t<512; ++t){
    const unsigned tgt = (unsigned)(t+1);

    // zx0 prefetch for A(t+1): issued now, completes during the wait
    int tn = (t<511) ? t+1 : 511;
    const _Float16* zsrc = zx0 + ((size_t)(tn*256 + wg)*32 + mt*16 + q*4)*16 + c;
    float pz0=(float)zsrc[0], pz1=(float)zsrc[16], pz2=(float)zsrc[32], pz3=(float)zsrc[48];

    // ---------- wait: detector (WG0 wave0) or private go poll -------------
    if (wg == 0 && wv == 0){
      // scan 256 slot lines; both wave-dwords of each must reach tgt
      for (;;){
        int ok = 1;
        #pragma unroll
        for (int m=0; m<4; ++m){
          unsigned long long v = LDU64(flags + (size_t)(l*4+m)*64);
          ok &= (int)(((unsigned)v >= tgt) & ((unsigned)(v>>32) >= tgt));
        }
        if (__ballot(ok) == 0xffffffffffffffffULL) break;
      }
      // parallel burst: 256 private go lines, 4 stores/lane
      #pragma unroll
      for (int m=0; m<4; ++m)
        STU(flags + 16384 + (size_t)(l*4+m)*64, tgt);
    } else {
      if (l == 0){
        while (LDU(go) < tgt) ;     // 1-2 pollers/line: no congestion
      }
      // divergence reconvergence: whole wave blocked until lane0 exits
    }
    asm volatile("" ::: "memory");  // no hoisting of h loads above the poll
    // NO fences: h0a[t]/h1a[t-1] lines are fresh by construction (t-indexed,
    // never cached by any XCD before this read; producers drained vmcnt
    // before slot stores; detector saw slots before go burst).

    // ---------- register-batched loads: all 64 fragments in flight --------
    const _Float16* h0c = h0a + (size_t)t*32768 + row*1024 + q*8;
    const _Float16* h1p = h1a + (size_t)(t-1)*32768 + row*1024 + q*8;
    half8 H1[32], H0[32];
    if (t > 0){
      #pragma unroll
      for (int s=0; s<32; ++s) H1[s] = AF(h1p, s);
    }
    #pragma unroll
    for (int s=0; s<32; ++s) H0[s] = AF(h0c, s);

    // ---------- merged compute: B(t) and A(t+1) ----------
    floatx4 aA0={0,0,0,0}, aA1={0,0,0,0};
    floatx4 aB0={b1v,b1v,b1v,b1v}, aB1={0,0,0,0};
    floatx4 aC0={0,0,0,0}, aC1={0,0,0,0};
    if (t > 0){
      #pragma unroll
      for (int s=0; s<16; ++s){
        aC0 = __builtin_amdgcn_mfma_f32_16x16x32_f16(H1[s],    BF(w2,s),    aC0,0,0,0);
        aC1 = __builtin_amdgcn_mfma_f32_16x16x32_f16(H1[16+s], BF(w2,16+s), aC1,0,0,0);
      }
    }
    #pragma unroll
    for (int s=0; s<16; ++s){
      aB0 = __builtin_amdgcn_mfma_f32_16x16x32_f16(H0[s],    BF(w1,s),    aB0,0,0,0);
      aB1 = __builtin_amdgcn_mfma_f32_16x16x32_f16(H0[16+s], BF(w1,16+s), aB1,0,0,0);
      aA0 = __builtin_amdgcn_mfma_f32_16x16x32_f16(H0[s],    BF(w0,s),    aA0,0,0,0);
      aA1 = __builtin_amdgcn_mfma_f32_16x16x32_f16(H0[16+s], BF(w0,16+s), aA1,0,0,0);
    }
    // B(t): h1(t)
    {
      floatx4 z1 = (aB0+aB1)+(aC0+aC1);
      gates_store(z1, c1, h1a + (size_t)t*32768, g, c, mt, q, wg);
    }
    // A(t+1): h0(t+1)
    if (t < 511){
      floatx4 z0 = aA0+aA1;
      z0[0]+=pz0; z0[1]+=pz1; z0[2]+=pz2; z0[3]+=pz3;
      gates_store(z0, c0, h0a + (size_t)(t+1)*32768, g, c, mt, q, wg);
    }
    // ---------- per-wave drain + plain-store slot (no RMW, no barrier) ----
    asm volatile("s_waitcnt vmcnt(0)" ::: "memory");
    if (l == 0) STU(slot + wv, (unsigned)(t+2));
  }
}

// ---------------- Y = H1 @ Wd + bd -----------------------------------------
__global__ __launch_bounds__(256) void wd_gemm(const _Float16* __restrict__ h1a,
                                               const _Float16* __restrict__ wda,
                                               const float* __restrict__ bd,
                                               float* __restrict__ y){
  int mb = blockIdx.x;   // 512 blocks of 32 rows (rows = t*32+b)
  int nb = blockIdx.y;   // 4 blocks of 128 cols
  int tid = threadIdx.x, wv = tid>>6, l = tid&63, q = l>>4, c = l&15;
  int mt = wv & 1, nh = wv >> 1;
  floatx4 acc[4];
  #pragma unroll
  for (int gg=0; gg<4; ++gg) acc[gg] = (floatx4){0.f,0.f,0.f,0.f};
  const _Float16* arow = h1a + (size_t)(mb*32 + mt*16 + c)*1024;
  #pragma unroll 4
  for (int ks=0; ks<32; ++ks){
    int kc = ks*4 + q;
    half8 a = *(const half8*)(arow + kc*8);
    #pragma unroll
    for (int gg=0; gg<4; ++gg){
      int nt = nb*8 + nh*4 + gg;
      half8 b = *(const half8*)(wda + ((size_t)(nt*128 + kc)*16 + c)*8);
      acc[gg] = __builtin_amdgcn_mfma_f32_16x16x32_f16(a,b,acc[gg],0,0,0);
    }
  }
  #pragma unroll
  for (int gg=0; gg<4; ++gg){
    int o = nb*128 + nh*64 + gg*16 + c;
    float bdv = bd[o];
    #pragma unroll
    for (int r=0;r<4;++r){
      int row = mb*32 + mt*16 + q*4 + r;
      int tt = row >> 5, bb = row & 31;
      y[(size_t)bb*262144 + tt*512 + o] = acc[gg][r] + bdv;
    }
  }
}

// ---------------------------------------------------------------------------
extern "C" void kernel_launch(void* const* d_in, const int* in_sizes, int n_in,
                              void* d_out, int out_size, void* d_ws, size_t ws_size,
                              hipStream_t stream){
  const float* x   = (const float*)d_in[0];
  const float* Wx0 = (const float*)d_in[1];
  const float* Wh0 = (const float*)d_in[2];
  const float* b0  = (const float*)d_in[3];
  const float* Wx1 = (const float*)d_in[4];
  const float* Wh1 = (const float*)d_in[5];
  const float* b1  = (const float*)d_in[6];
  const float* Wd  = (const float*)d_in[7];
  const float* bd  = (const float*)d_in[8];
  float* y = (float*)d_out;
  char* ws = (char*)d_ws;

  _Float16* wrec = (_Float16*)(ws + WREC_OFF);
  _Float16* wx0a = (_Float16*)(ws + WX0_OFF);
  _Float16* wda  = (_Float16*)(ws + WD_OFF);
  _Float16* xh   = (_Float16*)(ws + XH_OFF);
  _Float16* zx0  = (_Float16*)(ws + ZX0_OFF);
  _Float16* h1a  = (_Float16*)(ws + H1_OFF);
  _Float16* h0a  = (_Float16*)(ws + H0_OFF);
  unsigned int* flags = (unsigned int*)(ws + FLAGS_OFF);

  hipMemsetAsync(flags, 0, 131072, stream);
  conv_wrec<<<dim3(6144), dim3(256), 0, stream>>>(Wh0, Wx1, Wh1, wrec);
  conv_wx0 <<<dim3(1024), dim3(256), 0, stream>>>(Wx0, wx0a);
  conv_wd  <<<dim3(256),  dim3(256), 0, stream>>>(Wd, wda);
  conv_x   <<<dim3(8192), dim3(256), 0, stream>>>(x, xh);
  zx0_gemm <<<dim3(512,64), dim3(64), 0, stream>>>(xh, wx0a, b0, zx0);
  hipFuncSetAttribute((const void*)lstm_persist,
                      hipFuncAttributeMaxDynamicSharedMemorySize, 98304);
  lstm_persist<<<dim3(256), dim3(128), 98304, stream>>>(wrec, zx0, b1, h0a, h1a, flags);
  wd_gemm  <<<dim3(512,4), dim3(256), 0, stream>>>(h1a, wda, bd, y);
}

// Round 12
// 4568.319 us; speedup vs baseline: 1.1652x; 1.1441x over previous
//
#include <hip/hip_runtime.h>

// ---------------------------------------------------------------------------
// SimpleLSTM: 2-layer LSTM (B=32,T=512,D=512,H=1024) + output proj (O=512).
//   conv kernels : fp32 -> f16, weights rearranged into MFMA B-frag order
//   zx0_gemm     : Zx0[t][wg][m][c] = x@Wx0 + b0  (parallel over all T)
//   lstm_persist : 256 persistent WGs (1/CU), recurrent weights in LDS
//   wd_gemm      : Y = H1 @ Wd + bd
// R4-R16: tree barrier 14.5; uncached h stores 8.3; merged phase 7.6;
//   t-indexed h / no fences 6.6->5.8; batched loads 4.8; reader-detector +
//   zx0-shadow 4.66ms persist (best). Sync-structure variants all failed:
//   flat R9, fused R11, split R12, prefetch R13, all-poll R14, parallel
//   release R15, role-split R17, wave-decoupled R18. The period is pinned
//   by fabric latency, not sync topology.
// R19: WG-BLOCKED h LAYOUT — ONE WRITER PER LINE. Counter anomaly: WRITE
//   267MB for 64MB h payload (4.2x), invariant across ALL variants. Cause:
//   each 128B h line was assembled from 16 WGs' 4B partial stores ->
//   32B-sector HBM write-through + RMW; consumer fills came from HBM
//   (~900cy) not LLC, inflating both drain and fill legs. Now
//   h[t][wg][32 rows][4 cols]: each WG's output is 256B contiguous =
//   2 fully-dirty lines (16x 8B stores/wave, 4-col pack via extra shfl).
//   Consumers assemble fragments from 2x b64 block reads (same bytes).
//   wd_gemm switched to blocked reads. R16 barrier/zx0 placement intact.
// ---------------------------------------------------------------------------

typedef _Float16 half8  __attribute__((ext_vector_type(8)));
typedef float    floatx4 __attribute__((ext_vector_type(4)));
typedef unsigned long long u64;

// ws layout (bytes)
#define WREC_OFF   0UL            // [256 wg][3 mat][128 kc][16 c][8] f16 = 24 MiB
#define WX0_OFF    25165824UL     // [256 wg][64 kc][16 c][8] f16        = 4 MiB
#define WD_OFF     29360128UL     // [32 nt][128 kc][16 c][8] f16        = 1 MiB
#define XH_OFF     30408704UL     // [512 t][32 b][512 d] f16            = 16 MiB
#define ZX0_OFF    47185920UL     // [512 t][256 wg][32 m][16 c] f16     = 128 MiB
#define H1_OFF     181403648UL    // [512 t][256 wg][32 r][4] f16        = 32 MiB
#define H0_OFF     214958080UL    // [512 t][256 wg][32 r][4] f16        = 32 MiB
#define FLAGS_OFF  248512512UL    // 80 KiB: gcnt[32]@256B, go[256]@16K+256B

__device__ __forceinline__ float fsig(float x){ return 1.0f/(1.0f + __expf(-x)); }
__device__ __forceinline__ float ftanhf(float x){
  float e = __expf(2.0f*fabsf(x));
  float r = 1.0f - 2.0f/(e + 1.0f);
  return copysignf(r, x);
}

// ---------------- weight conversion ----------------------------------------
__global__ void conv_wrec(const float* __restrict__ Wh0,
                          const float* __restrict__ Wx1,
                          const float* __restrict__ Wh1,
                          _Float16* __restrict__ out){
  int idx = blockIdx.x*256 + threadIdx.x;          // ((wg*3+mat)*128+kc)*16+c
  if (idx >= 256*3*128*16) return;
  int c  = idx & 15;
  int t1 = idx >> 4;
  int kc = t1 & 127;
  int t2 = t1 >> 7;
  int mat = t2 % 3;
  int wg  = t2 / 3;
  const float* W = (mat==0) ? Wh0 : (mat==1) ? Wx1 : Wh1;
  int col = (c>>2)*1024 + wg*4 + (c&3);
  _Float16* o = out + (size_t)idx*8;
  #pragma unroll
  for (int j=0;j<8;++j) o[j] = (_Float16)W[(kc*8+j)*4096 + col];
}

__global__ void conv_wx0(const float* __restrict__ W, _Float16* __restrict__ out){
  int idx = blockIdx.x*256 + threadIdx.x;          // ((wg*64+kc)*16+c)
  if (idx >= 256*64*16) return;
  int c  = idx & 15;
  int kc = (idx >> 4) & 63;
  int wg = idx >> 10;
  int col = (c>>2)*1024 + wg*4 + (c&3);
  _Float16* o = out + (size_t)idx*8;
  #pragma unroll
  for (int j=0;j<8;++j) o[j] = (_Float16)W[(kc*8+j)*4096 + col];
}

__global__ void conv_wd(const float* __restrict__ W, _Float16* __restrict__ out){
  int idx = blockIdx.x*256 + threadIdx.x;          // ((nt*128+kc)*16+c)
  if (idx >= 32*128*16) return;
  int c  = idx & 15;
  int kc = (idx >> 4) & 127;
  int nt = idx >> 11;
  int col = nt*16 + c;
  _Float16* o = out + (size_t)idx*8;
  #pragma unroll
  for (int j=0;j<8;++j) o[j] = (_Float16)W[(kc*8+j)*512 + col];
}

// x[b][t][d] fp32 -> xh[t*32+b][d] f16  (time-major rows for zx0_gemm)
__global__ void conv_x(const float* __restrict__ x, _Float16* __restrict__ xh){
  int idx = blockIdx.x*256 + threadIdx.x;          // [bt][dq], dq = d/4
  if (idx >= 2097152) return;
  int dq = idx & 127;
  int bt = idx >> 7;          // t*32 + b
  int b  = bt & 31;
  int t  = bt >> 5;
  float4 v = ((const float4*)x)[(size_t)(b*512 + t)*128 + dq];
  _Float16* o = xh + (size_t)idx*4;
  o[0]=(_Float16)v.x; o[1]=(_Float16)v.y; o[2]=(_Float16)v.z; o[3]=(_Float16)v.w;
}

// ---------------- Zx0 = x @ Wx0 + b0 ---------------------------------------
__global__ __launch_bounds__(64) void zx0_gemm(const _Float16* __restrict__ xh,
                                               const _Float16* __restrict__ wx0a,
                                               const float* __restrict__ b0,
                                               _Float16* __restrict__ zx0){
  int t   = blockIdx.x;        // 512
  int wgg = blockIdx.y;        // 64 (covers 4 wg slices)
  int l = threadIdx.x, q = l>>4, c = l&15;
  floatx4 acc[2][4];
  #pragma unroll
  for (int g=0; g<4; ++g){
    int wg = wgg*4+g;
    float bv = b0[(c>>2)*1024 + wg*4 + (c&3)];
    acc[0][g] = (floatx4){bv,bv,bv,bv};
    acc[1][g] = (floatx4){bv,bv,bv,bv};
  }
  #pragma unroll 4
  for (int ks=0; ks<16; ++ks){
    int kc = ks*4 + q;
    half8 a0 = *(const half8*)(xh + (t*32      + c)*512 + kc*8);
    half8 a1 = *(const half8*)(xh + (t*32 + 16 + c)*512 + kc*8);
    #pragma unroll
    for (int g=0; g<4; ++g){
      int wg = wgg*4+g;
      half8 b = *(const half8*)(wx0a + ((size_t)(wg*64 + kc)*16 + c)*8);
      acc[0][g] = __builtin_amdgcn_mfma_f32_16x16x32_f16(a0,b,acc[0][g],0,0,0);
      acc[1][g] = __builtin_amdgcn_mfma_f32_16x16x32_f16(a1,b,acc[1][g],0,0,0);
    }
  }
  #pragma unroll
  for (int g=0; g<4; ++g){
    int wg = wgg*4+g;
    #pragma unroll
    for (int mt=0; mt<2; ++mt)
      #pragma unroll
      for (int r=0;r<4;++r){
        int m = mt*16 + q*4 + r;
        zx0[((size_t)(t*256 + wg)*32 + m)*16 + c] = (_Float16)acc[mt][g][r];
      }
  }
}

// ---------------- persistent recurrent kernel ------------------------------
// LDS: w0 (Wh0), w1 (Wx1), w2 (Wh1): [128 kc][16 c][8] each = 96 KiB total
#define BF(w, ks)     (*(const half8*)((w) + (((ks)*4 + q)*16 + c)*8))

#define LDU(p)  __hip_atomic_load((p),  __ATOMIC_RELAXED, __HIP_MEMORY_SCOPE_AGENT)
#define STU64(p,v) __hip_atomic_store((unsigned long long*)(p), (v), \
                                      __ATOMIC_RELAXED, __HIP_MEMORY_SCOPE_AGENT)

// blocked A-frag assembly: k in [32s+8q, 32s+8q+8) -> blocks 8s+2q, 8s+2q+1
union h8u { half8 h; u64 u[2]; };
__device__ __forceinline__ half8 LDBLK(const _Float16* base, int s, int q){
  // base = h + t*32768 + row*4 ; block b stride = 128 halves
  h8u v;
  const _Float16* p = base + (size_t)(8*s + 2*q)*128;
  v.u[0] = *(const u64*)(p);
  v.u[1] = *(const u64*)(p + 128);
  return v.h;
}

// gate exchange + cell update + ONE 8B store per row (4 cols packed): the
// WG's 32 rows x 8B land in 2 fully-dirty 128B lines (single-writer lines).
__device__ __forceinline__ void gates_store(floatx4 acc, float* cs,
    _Float16* dst, int g, int c, int mt, int q, int wg){
  #pragma unroll
  for (int r=0;r<4;++r){
    float v0 = acc[r];
    float v1 = __shfl_xor(v0, 4, 64);
    float v2 = __shfl_xor(v0, 8, 64);
    float v3 = __shfl_xor(v1, 8, 64);
    float zi = (g==0)?v0:(g==1)?v1:(g==2)?v2:v3;
    float zf = (g==0)?v1:(g==1)?v0:(g==2)?v3:v2;
    float zg = (g==0)?v2:(g==1)?v3:(g==2)?v0:v1;
    float zo = (g==0)?v3:(g==1)?v2:(g==2)?v1:v0;
    float cn = fsig(zf)*cs[r] + fsig(zi)*ftanhf(zg);
    cs[r] = cn;
    float hv = fsig(zo)*ftanhf(cn);
    unsigned hb16 = (unsigned)__builtin_bit_cast(unsigned short, (_Float16)hv);
    unsigned up   = (unsigned)__shfl_xor((int)hb16, 1, 64);
    unsigned pair = hb16 | (up<<16);                    // cols (c, c+1) at even c
    unsigned pair2 = (unsigned)__shfl_xor((int)pair, 2, 64);  // cols (c+2, c+3)
    if (g==0 && (c&3)==0){
      u64 w = (u64)pair | ((u64)pair2 << 32);           // cols 0..3 of this wg
      STU64(dst + (size_t)wg*128 + (mt*16 + q*4 + r)*4, w);
    }
  }
}

__global__ __launch_bounds__(128, 1) void lstm_persist(
    const _Float16* __restrict__ wrec, const _Float16* __restrict__ zx0,
    const float* __restrict__ b1g, _Float16* __restrict__ h0a,
    _Float16* __restrict__ h1a, unsigned int* __restrict__ flags)
{
  extern __shared__ _Float16 lds[];
  _Float16* w0  = lds;            // 16384 halves
  _Float16* w1  = lds + 16384;
  _Float16* w2  = lds + 32768;

  const int wg = blockIdx.x, tid = threadIdx.x;
  const int wv = tid>>6, l = tid&63, q = l>>4, c = l&15;
  const int g = (c>>2);           // gate of own column
  const int mt = wv;              // wave0 rows 0-15, wave1 rows 16-31
  const int row = mt*16 + c;      // A-frag row this lane loads
  const int grp = wg >> 3;        // 32 groups of 8

  unsigned int* gcnt = flags + grp*64;        // leaf lines, 256B apart
  unsigned int* go   = flags + 4096;          // PRIVATE go[wg] @16KiB + wg*256B

  { // stage this WG's weight slice: 98304 B = 6144 uint4
    const uint4* src = (const uint4*)(wrec + (size_t)wg*49152);
    uint4* dst = (uint4*)lds;
    for (int i=tid; i<6144; i+=128) dst[i] = src[i];
  }
  float c0[4] = {0,0,0,0}, c1[4] = {0,0,0,0};
  const float b1v = b1g[g*1024 + wg*4 + (c&3)];
  __syncthreads();

  // ---------- prologue: A(0): h0(0) = act(Zx0[0]) (h0(-1)=0) ----------
  {
    const _Float16* zsrc = zx0 + ((size_t)wg*32 + mt*16 + q*4)*16 + c;
    floatx4 a;
    a[0]=(float)zsrc[0]; a[1]=(float)zsrc[16]; a[2]=(float)zsrc[32]; a[3]=(float)zsrc[48];
    gates_store(a, c0, h0a, g, c, mt, q, wg);   // t = 0
  }

  for (int t=0; t<512; ++t){
    __syncthreads();   // drains vmcnt: h0(t)/h1(t-1) stores visible at LLC

    // ---------- barrier arrive: one leaf RMW per WG (no root level) -------
    const unsigned tgt = (unsigned)(t+1);
    if (tid == 0)
      __hip_atomic_fetch_add(gcnt, 1u, __ATOMIC_RELAXED,
                             __HIP_MEMORY_SCOPE_AGENT);

    // ---------- zx0 prefetch for A(t+1): completes in the wait shadow ----
    int tn = (t<511) ? t+1 : 511;
    const _Float16* zsrc = zx0 + ((size_t)(tn*256 + wg)*32 + mt*16 + q*4)*16 + c;
    float pz0=(float)zsrc[0], pz1=(float)zsrc[16], pz2=(float)zsrc[32], pz3=(float)zsrc[48];

    // ---------- detect + release ----------
    if (wg == 0 && wv == 0){
      // WG0 wave0: reader-detector. 32 lanes poll 32 leaf lines (1 each),
      // then all 64 lanes broadcast 256 private go lines in parallel.
      const unsigned thr = 8u*tgt;
      const unsigned int* myleaf = flags + l*64;
      for (;;){
        unsigned v = 0xffffffffu;
        if (l < 32)
          v = __hip_atomic_load(myleaf, __ATOMIC_RELAXED,
                                __HIP_MEMORY_SCOPE_AGENT);
        if (__ballot(v >= thr) == 0xffffffffffffffffULL) break;
      }
      #pragma unroll
      for (int k2=0; k2<4; ++k2)
        __hip_atomic_store(go + (size_t)(l*4+k2)*64, tgt,
                           __ATOMIC_RELAXED, __HIP_MEMORY_SCOPE_AGENT);
    } else if (wg != 0 && tid == 0){
      // tight poll on private line (1 writer, 1 poller — no congestion)
      while (__hip_atomic_load(go + (size_t)wg*64, __ATOMIC_RELAXED,
                               __HIP_MEMORY_SCOPE_AGENT) < tgt)
        ;
    }
    __syncthreads();
    // NO acquire fence: h0a[t]/h1a[t-1] lines are fresh by construction
    // (never cached by any XCD before this read; producers stored uncached
    // to LLC, single-writer full lines). zx0/weights are read-only.

    // ---------- register-batched blocked loads: all frags in flight -------
    const _Float16* h0c = h0a + (size_t)t*32768 + row*4;
    const _Float16* h1p = h1a + (size_t)(t-1)*32768 + row*4;
    half8 H1[32], H0[32];
    if (t > 0){
      #pragma unroll
      for (int s=0; s<32; ++s) H1[s] = LDBLK(h1p, s, q);
    }
    #pragma unroll
    for (int s=0; s<32; ++s) H0[s] = LDBLK(h0c, s, q);

    // ---------- merged compute: B(t) and A(t+1) ----------
    floatx4 aA0={0,0,0,0}, aA1={0,0,0,0};
    floatx4 aB0={b1v,b1v,b1v,b1v}, aB1={0,0,0,0};
    floatx4 aC0={0,0,0,0}, aC1={0,0,0,0};
    if (t > 0){
      #pragma unroll
      for (int s=0; s<16; ++s){
        aC0 = __builtin_amdgcn_mfma_f32_16x16x32_f16(H1[s],    BF(w2,s),    aC0,0,0,0);
        aC1 = __builtin_amdgcn_mfma_f32_16x16x32_f16(H1[16+s], BF(w2,16+s), aC1,0,0,0);
      }
    }
    #pragma unroll
    for (int s=0; s<16; ++s){
      aB0 = __builtin_amdgcn_mfma_f32_16x16x32_f16(H0[s],    BF(w1,s),    aB0,0,0,0);
      aB1 = __builtin_amdgcn_mfma_f32_16x16x32_f16(H0[16+s], BF(w1,16+s), aB1,0,0,0);
      aA0 = __builtin_amdgcn_mfma_f32_16x16x32_f16(H0[s],    BF(w0,s),    aA0,0,0,0);
      aA1 = __builtin_amdgcn_mfma_f32_16x16x32_f16(H0[16+s], BF(w0,16+s), aA1,0,0,0);
    }
    // B(t): h1(t)
    {
      floatx4 z1 = (aB0+aB1)+(aC0+aC1);
      gates_store(z1, c1, h1a + (size_t)t*32768, g, c, mt, q, wg);
    }
    // A(t+1): h0(t+1)
    if (t < 511){
      floatx4 z0 = aA0+aA1;
      z0[0]+=pz0; z0[1]+=pz1; z0[2]+=pz2; z0[3]+=pz3;
      gates_store(z0, c0, h0a + (size_t)(t+1)*32768, g, c, mt, q, wg);
    }
  }
}

// ---------------- Y = H1 @ Wd + bd -----------------------------------------
// h1a is blocked: [512 t][256 blk][32 r][4]; row t = mb, brow = mt*16+c.
__global__ __launch_bounds__(256) void wd_gemm(const _Float16* __restrict__ h1a,
                                               const _Float16* __restrict__ wda,
                                               const float* __restrict__ bd,
                                               float* __restrict__ y){
  int mb = blockIdx.x;   // 512 blocks of 32 rows (rows = t*32+b); t == mb
  int nb = blockIdx.y;   // 4 blocks of 128 cols
  int tid = threadIdx.x, wv = tid>>6, l = tid&63, q = l>>4, c = l&15;
  int mt = wv & 1, nh = wv >> 1;
  floatx4 acc[4];
  #pragma unroll
  for (int gg=0; gg<4; ++gg) acc[gg] = (floatx4){0.f,0.f,0.f,0.f};
  const _Float16* abase = h1a + (size_t)mb*32768 + (mt*16 + c)*4;
  #pragma unroll 4
  for (int ks=0; ks<32; ++ks){
    int kc = ks*4 + q;
    h8u va;
    const _Float16* p = abase + (size_t)(2*kc)*128;
    va.u[0] = *(const u64*)(p);
    va.u[1] = *(const u64*)(p + 128);
    half8 a = va.h;
    #pragma unroll
    for (int gg=0; gg<4; ++gg){
      int nt = nb*8 + nh*4 + gg;
      half8 b = *(const half8*)(wda + ((size_t)(nt*128 + kc)*16 + c)*8);
      acc[gg] = __builtin_amdgcn_mfma_f32_16x16x32_f16(a,b,acc[gg],0,0,0);
    }
  }
  #pragma unroll
  for (int gg=0; gg<4; ++gg){
    int o = nb*128 + nh*64 + gg*16 + c;
    float bdv = bd[o];
    #pragma unroll
    for (int r=0;r<4;++r){
      int row = mb*32 + mt*16 + q*4 + r;
      int tt = row >> 5, bb = row & 31;
      y[(size_t)bb*262144 + tt*512 + o] = acc[gg][r] + bdv;
    }
  }
}

// ---------------------------------------------------------------------------
extern "C" void kernel_launch(void* const* d_in, const int* in_sizes, int n_in,
                              void* d_out, int out_size, void* d_ws, size_t ws_size,
                              hipStream_t stream){
  const float* x   = (const float*)d_in[0];
  const float* Wx0 = (const float*)d_in[1];
  const float* Wh0 = (const float*)d_in[2];
  const float* b0  = (const float*)d_in[3];
  const float* Wx1 = (const float*)d_in[4];
  const float* Wh1 = (const float*)d_in[5];
  const float* b1  = (const float*)d_in[6];
  const float* Wd  = (const float*)d_in[7];
  const float* bd  = (const float*)d_in[8];
  float* y = (float*)d_out;
  char* ws = (char*)d_ws;

  _Float16* wrec = (_Float16*)(ws + WREC_OFF);
  _Float16* wx0a = (_Float16*)(ws + WX0_OFF);
  _Float16* wda  = (_Float16*)(ws + WD_OFF);
  _Float16* xh   = (_Float16*)(ws + XH_OFF);
  _Float16* zx0  = (_Float16*)(ws + ZX0_OFF);
  _Float16* h1a  = (_Float16*)(ws + H1_OFF);
  _Float16* h0a  = (_Float16*)(ws + H0_OFF);
  unsigned int* flags = (unsigned int*)(ws + FLAGS_OFF);

  hipMemsetAsync(flags, 0, 81920, stream);
  conv_wrec<<<dim3(6144), dim3(256), 0, stream>>>(Wh0, Wx1, Wh1, wrec);
  conv_wx0 <<<dim3(1024), dim3(256), 0, stream>>>(Wx0, wx0a);
  conv_wd  <<<dim3(256),  dim3(256), 0, stream>>>(Wd, wda);
  conv_x   <<<dim3(8192), dim3(256), 0, stream>>>(x, xh);
  zx0_gemm <<<dim3(512,64), dim3(64), 0, stream>>>(xh, wx0a, b0, zx0);
  hipFuncSetAttribute((const void*)lstm_persist,
                      hipFuncAttributeMaxDynamicSharedMemorySize, 98304);
  lstm_persist<<<dim3(256), dim3(128), 98304, stream>>>(wrec, zx0, b1, h0a, h1a, flags);
  wd_gemm  <<<dim3(512,4), dim3(256), 0, stream>>>(h1a, wda, bd, y);
}